// Round 13
// baseline (1057.658 us; speedup 1.0000x reference)
//
#include <hip/hip_runtime.h>
#include <cstdint>

// Problem constants
constexpr int Cc = 95;    // input channels
constexpr int Hh = 128;   // hidden
constexpr int G  = 512;   // 4*H gates
constexpr int Bb = 256;   // batch
constexpr int Tt = 1000;  // timesteps
#define EPSBN 1e-5f

typedef _Float16 half8  __attribute__((ext_vector_type(8)));
typedef _Float16 half2v __attribute__((ext_vector_type(2)));
typedef float floatx4 __attribute__((ext_vector_type(4)));
typedef float float4u __attribute__((ext_vector_type(4), aligned(4)));
typedef float float2u __attribute__((ext_vector_type(2), aligned(4)));

__device__ __forceinline__ unsigned pku(float a, float b) {
  return __builtin_bit_cast(unsigned, __builtin_amdgcn_cvt_pkrtz(a, b));
}
__device__ __forceinline__ half2v pkh(float a, float b) {
  return __builtin_bit_cast(half2v, __builtin_amdgcn_cvt_pkrtz(a, b));
}
__device__ __forceinline__ half2v bch(unsigned x) {
  return __builtin_bit_cast(half2v, x);
}
__device__ __forceinline__ float fdot2(half2v a, half2v b, float c) {
#if __has_builtin(__builtin_amdgcn_fdot2)
  return __builtin_amdgcn_fdot2(a, b, c, false);
#else
  return fmaf((float)a[0], (float)b[0], fmaf((float)a[1], (float)b[1], c));
#endif
}
__device__ __forceinline__ float fsigm(float y) {
  y = fminf(30.f, fmaxf(-30.f, y));
  float e = __expf(-y);
  return __fdividef(1.f, 1.f + e);
}
__device__ __forceinline__ float ftanh2(float x) {  // tanh via exp(2x)
  float y = fminf(30.f, fmaxf(-30.f, 2.f * x));
  float e = __expf(y);
  return __fdividef(e - 1.f, e + 1.f);
}

// ---------------------------------------------------------------------------
// K0: fold BN into W_ih -> Wp f16 [512][96] (k=95 padded 0),
// bias'[g] = b_ih+b_hh + sum_c sft_c * W_ih[g][c].
// ---------------------------------------------------------------------------
__global__ __launch_bounds__(512)
void k0_prep(const float* __restrict__ gamma, const float* __restrict__ beta,
             const float* __restrict__ rmean, const float* __restrict__ rvar,
             const float* __restrict__ W_ih, const float* __restrict__ b_ih,
             const float* __restrict__ b_hh, float* __restrict__ biasp,
             _Float16* __restrict__ Wp) {
  __shared__ float scl[Cc], sft[Cc];
  const int t = threadIdx.x;
  if (t < Cc) {
    float s = gamma[t] * rsqrtf(rvar[t] + EPSBN);
    scl[t] = s;
    sft[t] = beta[t] - rmean[t] * s;
  }
  __syncthreads();
  float acc = b_ih[t] + b_hh[t];
  const float* wr = W_ih + (size_t)t * Cc;
  for (int c = 0; c < Cc; ++c) {
    float w = wr[c];
    acc = fmaf(sft[c], w, acc);
    Wp[t * 96 + c] = (_Float16)(w * scl[c]);
  }
  Wp[t * 96 + 95] = (_Float16)0.f;
  biasp[t] = acc;
}

// ---------------------------------------------------------------------------
// K1: xw[m][g] = f16(x_f16 . Wp^T + bias') via mfma (r12-proven, f16 stores).
// ---------------------------------------------------------------------------
template <int TC>
__global__ __launch_bounds__(512)
void k1_mfma(const float* __restrict__ x, const _Float16* __restrict__ Wp,
             const float* __restrict__ biasp, _Float16* __restrict__ xw,
             int t0) {
  const int tid = threadIdx.x;
  const int wave = tid >> 6, lane = tid & 63;
  const int wm = wave >> 2, wn = wave & 3;
  const int row0 = blockIdx.x * 64 + wm * 32;
  const int nb0 = wn * 128;
  const int l15 = lane & 15, lg = lane >> 4;

  uint4 afr[2][3];
#pragma unroll
  for (int mt = 0; mt < 2; ++mt) {
    int m = row0 + mt * 16 + l15;
    int b = m / TC, tl = m - b * TC;
    const float* xr = x + ((size_t)b * Tt + t0 + tl) * Cc;
#pragma unroll
    for (int kk = 0; kk < 3; ++kk) {
      int k = kk * 32 + lg * 8;
      float4u p0 = *reinterpret_cast<const float4u*>(xr + k);
      float e4, e5, e6, e7;
      if (k == 88) {
        float2u q = *reinterpret_cast<const float2u*>(xr + 92);
        e4 = q[0]; e5 = q[1]; e6 = xr[94]; e7 = 0.f;
      } else {
        float4u p1 = *reinterpret_cast<const float4u*>(xr + k + 4);
        e4 = p1[0]; e5 = p1[1]; e6 = p1[2]; e7 = p1[3];
      }
      afr[mt][kk] = make_uint4(pku(p0[0], p0[1]), pku(p0[2], p0[3]),
                               pku(e4, e5), pku(e6, e7));
    }
  }

  floatx4 acc[2][8] = {};
#pragma unroll
  for (int kk = 0; kk < 3; ++kk)
#pragma unroll
    for (int nt = 0; nt < 8; ++nt) {
      const _Float16* wrow = Wp + (size_t)(nb0 + nt * 16 + l15) * 96 + lg * 8;
      uint4 bfr = *reinterpret_cast<const uint4*>(wrow + kk * 32);
      half8 bv = __builtin_bit_cast(half8, bfr);
      acc[0][nt] = __builtin_amdgcn_mfma_f32_16x16x32_f16(
          __builtin_bit_cast(half8, afr[0][kk]), bv, acc[0][nt], 0, 0, 0);
      acc[1][nt] = __builtin_amdgcn_mfma_f32_16x16x32_f16(
          __builtin_bit_cast(half8, afr[1][kk]), bv, acc[1][nt], 0, 0, 0);
    }

#pragma unroll
  for (int nt = 0; nt < 8; ++nt) {
    int n = nb0 + nt * 16 + l15;
    float bias = biasp[n];
#pragma unroll
    for (int mt = 0; mt < 2; ++mt) {
      int rbase = row0 + mt * 16 + lg * 4;
#pragma unroll
      for (int r = 0; r < 4; ++r)
        xw[(size_t)(rbase + r) * G + n] = (_Float16)(acc[mt][nt][r] + bias);
    }
  }
}

// ---------------------------------------------------------------------------
// K2: hybrid-pipe LSTM recurrence. 256 blocks x 256 thr (4 waves, 1/SIMD).
// Per wave (units 32w..32w+32): gates g,o via 16 MFMA (matrix pipe, afr
// 64 VGPR); gates i,f via per-lane fdot2 rows (VALU pipe, wd 64 VGPR) —
// the two pipes run concurrently (m114), halving the dominant MFMA-pipe
// term (32x17 -> 16x17 cyc). Lane-duplicate pairs (l15, l15+8) compute
// i resp. f for the same unit; one shfl_xor(8) exchanges them.
// Ring holds raw f16 (cvt at consume, 4 steps after load — r12 lesson).
// ---------------------------------------------------------------------------
template <int TC>
__global__ __launch_bounds__(256, 1)
void k2_lstm(const _Float16* __restrict__ xw, const float* __restrict__ W_hh,
             float* __restrict__ hstate, float* __restrict__ cstate,
             const float* __restrict__ fc_w, const float* __restrict__ fc_b,
             float* __restrict__ out, int t0) {
  __shared__ __align__(16) _Float16 h2[2][Hh];
  __shared__ float h32[Hh];

  const int b = blockIdx.x;
  const int tid = threadIdx.x;
  const int w = tid >> 6, lane = tid & 63;
  const int l15 = lane & 15, lg = lane >> 4;
  const int hh = l15 & 1, rr = (l15 >> 1) & 3;   // l15>=8 duplicates
  const int u = 32 * w + 16 * hh + 4 * lg + rr;  // unit this lane updates
  const bool owner = (l15 < 8);

  // fdot2 weights: W_hh row (i-row for l15<8, f-row for l15>=8) -> 64 half2
  half2v wd[64];
  {
    const int rowd = (owner ? 0 : Hh) + u;  // q=0 (i) or q=1 (f)
    const float2* wr0 = reinterpret_cast<const float2*>(W_hh + (size_t)rowd * Hh);
#pragma unroll
    for (int i = 0; i < 64; ++i) {
      float2 t = wr0[i];
      wd[i] = pkh(t.x, t.y);
    }
  }

  // MFMA A-frags: gates q=2 (g), q=3 (o): 4 tiles x 4 kc -> 64 VGPR
  uint4 afr[4][4];
#pragma unroll
  for (int q2 = 0; q2 < 2; ++q2)
#pragma unroll
    for (int h2i = 0; h2i < 2; ++h2i) {
      const float* wr = W_hh +
          (size_t)((q2 + 2) * 128 + 32 * w + 16 * h2i + l15) * Hh + 8 * lg;
#pragma unroll
      for (int kc = 0; kc < 4; ++kc) {
        float4u p0 = *reinterpret_cast<const float4u*>(wr + 32 * kc);
        float4u p1 = *reinterpret_cast<const float4u*>(wr + 32 * kc + 4);
        afr[2 * q2 + h2i][kc] = make_uint4(pku(p0[0], p0[1]), pku(p0[2], p0[3]),
                                           pku(p1[0], p1[1]), pku(p1[2], p1[3]));
      }
    }

  float creg = 0.f, hreg = 0.f;
  if (t0 == 0) {
    if (owner) h2[0][u] = (_Float16)0.f;
  } else {
    creg = cstate[b * Hh + u];
    hreg = hstate[b * Hh + u];
    if (owner) h2[0][u] = (_Float16)hreg;
  }
  __syncthreads();

  const _Float16* xwb = xw + (size_t)b * TC * G + u;

  // 4-deep prefetch ring, raw f16 regs (no cvt at refill!)
  _Float16 ri[4], rf[4], rg[4], ro[4];
#pragma unroll
  for (int i = 0; i < 4; ++i) {
    if (i < TC) {
      const _Float16* xp = xwb + (size_t)i * G;
      ri[i] = xp[0 * 128]; rf[i] = xp[1 * 128];
      rg[i] = xp[2 * 128]; ro[i] = xp[3 * 128];
    } else {
      ri[i] = rf[i] = rg[i] = ro[i] = (_Float16)0.f;
    }
  }

#define K2_STEP(TL, SL)                                                        \
  {                                                                            \
    const int tl_ = (TL);                                                      \
    const int rb_ = tl_ & 1;                                                   \
    float ci = (float)ri[SL], cf = (float)rf[SL];                              \
    float cg = (float)rg[SL], co = (float)ro[SL];                              \
    if (tl_ + 4 < TC) {                                                        \
      const _Float16* xp_ = xwb + (size_t)(tl_ + 4) * G;                       \
      ri[SL] = xp_[0 * 128]; rf[SL] = xp_[1 * 128];                            \
      rg[SL] = xp_[2 * 128]; ro[SL] = xp_[3 * 128];                            \
    }                                                                          \
    uint4 bfr[4];                                                              \
    _Pragma("unroll") for (int kc = 0; kc < 4; ++kc)                           \
        bfr[kc] = *reinterpret_cast<const uint4*>(&h2[rb_][32 * kc + 8 * lg]); \
    const uint4* hp_ = reinterpret_cast<const uint4*>(&h2[rb_][0]);            \
    float a0 = 0.f, a1 = 0.f, a2 = 0.f, a3 = 0.f;                              \
    _Pragma("unroll") for (int kk = 0; kk < 16; ++kk) {                        \
      uint4 hv = hp_[kk];                                                      \
      a0 = fdot2(wd[4 * kk + 0], bch(hv.x), a0);                               \
      a1 = fdot2(wd[4 * kk + 1], bch(hv.y), a1);                               \
      a2 = fdot2(wd[4 * kk + 2], bch(hv.z), a2);                               \
      a3 = fdot2(wd[4 * kk + 3], bch(hv.w), a3);                               \
    }                                                                          \
    floatx4 acc[4] = {};                                                       \
    _Pragma("unroll") for (int kc = 0; kc < 4; ++kc)                           \
        _Pragma("unroll") for (int t_ = 0; t_ < 4; ++t_)                       \
            acc[t_] = __builtin_amdgcn_mfma_f32_16x16x32_f16(                  \
                __builtin_bit_cast(half8, afr[t_][kc]),                        \
                __builtin_bit_cast(half8, bfr[kc]), acc[t_], 0, 0, 0);         \
    float mydot = (a0 + a1) + (a2 + a3);                                       \
    float othd = __shfl_xor(mydot, 8);                                         \
    float dot_i = owner ? mydot : othd;                                        \
    float dot_f = owner ? othd : mydot;                                        \
    float eg0 = hh ? acc[1][0] : acc[0][0];                                    \
    float eg1 = hh ? acc[1][1] : acc[0][1];                                    \
    float eg2 = hh ? acc[1][2] : acc[0][2];                                    \
    float eg3 = hh ? acc[1][3] : acc[0][3];                                    \
    float glo = (rr & 1) ? eg1 : eg0;                                          \
    float ghi = (rr & 1) ? eg3 : eg2;                                          \
    float gg_ = (rr & 2) ? ghi : glo;                                          \
    float eo0 = hh ? acc[3][0] : acc[2][0];                                    \
    float eo1 = hh ? acc[3][1] : acc[2][1];                                    \
    float eo2 = hh ? acc[3][2] : acc[2][2];                                    \
    float eo3 = hh ? acc[3][3] : acc[2][3];                                    \
    float olo = (rr & 1) ? eo1 : eo0;                                          \
    float ohi = (rr & 1) ? eo3 : eo2;                                          \
    float go_ = (rr & 2) ? ohi : olo;                                          \
    float i_ = fsigm(dot_i + ci);                                              \
    float f_ = fsigm(dot_f + cf);                                              \
    float g_ = ftanh2(gg_ + cg);                                               \
    float o_ = fsigm(go_ + co);                                                \
    creg = fmaf(f_, creg, i_ * g_);                                            \
    hreg = o_ * ftanh2(creg);                                                  \
    if (owner) h2[rb_ ^ 1][u] = (_Float16)hreg;                                \
    asm volatile("s_waitcnt lgkmcnt(0)" ::: "memory");                         \
    __builtin_amdgcn_s_barrier();                                              \
    __builtin_amdgcn_sched_barrier(0);                                         \
  }

  int tl = 0;
  for (; tl + 4 <= TC; tl += 4) {
    K2_STEP(tl + 0, 0)
    K2_STEP(tl + 1, 1)
    K2_STEP(tl + 2, 2)
    K2_STEP(tl + 3, 3)
  }
  if constexpr ((TC & 3) >= 1) K2_STEP(TC & ~3, 0)
  if constexpr ((TC & 3) >= 2) K2_STEP((TC & ~3) + 1, 1)
  if constexpr ((TC & 3) >= 3) K2_STEP((TC & ~3) + 2, 2)
#undef K2_STEP

  if (owner) {
    hstate[b * Hh + u] = hreg;
    cstate[b * Hh + u] = creg;
    h32[u] = hreg;
  }
  __syncthreads();

  if (t0 + TC == Tt && tid < 4) {
    float s = fc_b[tid];
    for (int jj = 0; jj < Hh; ++jj) s = fmaf(h32[jj], fc_w[tid * Hh + jj], s);
    out[b * 4 + tid] = s;
  }
}

// ---------------------------------------------------------------------------
template <int TC>
static void run_chunks(const float* x, const float* gamma, const float* beta,
                       const float* rmean, const float* rvar,
                       const float* W_ih, const float* W_hh,
                       const float* b_ih, const float* b_hh,
                       const float* fc_w, const float* fc_b, float* out,
                       void* d_ws, hipStream_t stream) {
  char* ws = reinterpret_cast<char*>(d_ws);
  _Float16* xwp = reinterpret_cast<_Float16*>(ws);
  size_t off = (size_t)Bb * TC * G * 4;  // f32-sized reservation (safe)
  float* hst = reinterpret_cast<float*>(ws + off);  off += (size_t)Bb * Hh * 4;
  float* cst = reinterpret_cast<float*>(ws + off);  off += (size_t)Bb * Hh * 4;
  float* bia = reinterpret_cast<float*>(ws + off);  off += 512 * 4;
  off = (off + 15) & ~(size_t)15;
  _Float16* Wp = reinterpret_cast<_Float16*>(ws + off);

  k0_prep<<<dim3(1), dim3(512), 0, stream>>>(gamma, beta, rmean, rvar, W_ih,
                                             b_ih, b_hh, bia, Wp);
  for (int t0 = 0; t0 < Tt; t0 += TC) {
    k1_mfma<TC><<<dim3(Bb * TC / 64), dim3(512), 0, stream>>>(x, Wp, bia, xwp,
                                                              t0);
    k2_lstm<TC><<<dim3(Bb), dim3(256), 0, stream>>>(xwp, W_hh, hst, cst, fc_w,
                                                    fc_b, out, t0);
  }
}

extern "C" void kernel_launch(void* const* d_in, const int* in_sizes, int n_in,
                              void* d_out, int out_size, void* d_ws,
                              size_t ws_size, hipStream_t stream) {
  const float* x     = (const float*)d_in[0];
  const float* gamma = (const float*)d_in[1];
  const float* beta  = (const float*)d_in[2];
  const float* rmean = (const float*)d_in[3];
  const float* rvar  = (const float*)d_in[4];
  const float* W_ih  = (const float*)d_in[5];
  const float* W_hh  = (const float*)d_in[6];
  const float* b_ih  = (const float*)d_in[7];
  const float* b_hh  = (const float*)d_in[8];
  const float* fc_w  = (const float*)d_in[9];
  const float* fc_b  = (const float*)d_in[10];
  float* out = (float*)d_out;

  auto need = [](int tc) {
    return (size_t)Bb * tc * G * 4 + 2 * (size_t)Bb * Hh * 4 + 512 * 4 + 16 +
           (size_t)512 * 96 * 2;
  };

  if (ws_size >= need(250)) {
    run_chunks<250>(x, gamma, beta, rmean, rvar, W_ih, W_hh, b_ih, b_hh, fc_w,
                    fc_b, out, d_ws, stream);
  } else if (ws_size >= need(125)) {
    run_chunks<125>(x, gamma, beta, rmean, rvar, W_ih, W_hh, b_ih, b_hh, fc_w,
                    fc_b, out, d_ws, stream);
  } else if (ws_size >= need(50)) {
    run_chunks<50>(x, gamma, beta, rmean, rvar, W_ih, W_hh, b_ih, b_hh, fc_w,
                   fc_b, out, d_ws, stream);
  } else {
    run_chunks<10>(x, gamma, beta, rmean, rvar, W_ih, W_hh, b_ih, b_hh, fc_w,
                   fc_b, out, d_ws, stream);
  }
}

// Round 14
// 900.611 us; speedup vs baseline: 1.1744x; 1.1744x over previous
//
#include <hip/hip_runtime.h>
#include <cstdint>

// Problem constants
constexpr int Cc = 95;    // input channels
constexpr int Hh = 128;   // hidden
constexpr int G  = 512;   // 4*H gates
constexpr int Bb = 256;   // batch
constexpr int Tt = 1000;  // timesteps
#define EPSBN 1e-5f

typedef _Float16 half8  __attribute__((ext_vector_type(8)));
typedef float floatx4 __attribute__((ext_vector_type(4)));
typedef float float4u __attribute__((ext_vector_type(4), aligned(4)));
typedef float float2u __attribute__((ext_vector_type(2), aligned(4)));

__device__ __forceinline__ unsigned pku(float a, float b) {
  return __builtin_bit_cast(unsigned, __builtin_amdgcn_cvt_pkrtz(a, b));
}
__device__ __forceinline__ float fsigm(float y) {
  y = fminf(30.f, fmaxf(-30.f, y));
  float e = __expf(-y);
  return __fdividef(1.f, 1.f + e);
}
__device__ __forceinline__ float ftanh2(float x) {  // tanh via exp(2x)
  float y = fminf(30.f, fmaxf(-30.f, 2.f * x));
  float e = __expf(y);
  return __fdividef(e - 1.f, e + 1.f);
}

// ---------------------------------------------------------------------------
// K0: fold BN into W_ih -> Wp f16 [512][96] (k=95 padded 0),
// bias'[g] = b_ih+b_hh + sum_c sft_c * W_ih[g][c].
// ---------------------------------------------------------------------------
__global__ __launch_bounds__(512)
void k0_prep(const float* __restrict__ gamma, const float* __restrict__ beta,
             const float* __restrict__ rmean, const float* __restrict__ rvar,
             const float* __restrict__ W_ih, const float* __restrict__ b_ih,
             const float* __restrict__ b_hh, float* __restrict__ biasp,
             _Float16* __restrict__ Wp) {
  __shared__ float scl[Cc], sft[Cc];
  const int t = threadIdx.x;
  if (t < Cc) {
    float s = gamma[t] * rsqrtf(rvar[t] + EPSBN);
    scl[t] = s;
    sft[t] = beta[t] - rmean[t] * s;
  }
  __syncthreads();
  float acc = b_ih[t] + b_hh[t];
  const float* wr = W_ih + (size_t)t * Cc;
  for (int c = 0; c < Cc; ++c) {
    float w = wr[c];
    acc = fmaf(sft[c], w, acc);
    Wp[t * 96 + c] = (_Float16)(w * scl[c]);
  }
  Wp[t * 96 + 95] = (_Float16)0.f;
  biasp[t] = acc;
}

// ---------------------------------------------------------------------------
// K1: xw[m][g] = f16(x_f16 . Wp^T + bias') via mfma (r12-proven, f16 stores).
// ---------------------------------------------------------------------------
template <int TC>
__global__ __launch_bounds__(512)
void k1_mfma(const float* __restrict__ x, const _Float16* __restrict__ Wp,
             const float* __restrict__ biasp, _Float16* __restrict__ xw,
             int t0) {
  const int tid = threadIdx.x;
  const int wave = tid >> 6, lane = tid & 63;
  const int wm = wave >> 2, wn = wave & 3;
  const int row0 = blockIdx.x * 64 + wm * 32;
  const int nb0 = wn * 128;
  const int l15 = lane & 15, lg = lane >> 4;

  uint4 afr[2][3];
#pragma unroll
  for (int mt = 0; mt < 2; ++mt) {
    int m = row0 + mt * 16 + l15;
    int b = m / TC, tl = m - b * TC;
    const float* xr = x + ((size_t)b * Tt + t0 + tl) * Cc;
#pragma unroll
    for (int kk = 0; kk < 3; ++kk) {
      int k = kk * 32 + lg * 8;
      float4u p0 = *reinterpret_cast<const float4u*>(xr + k);
      float e4, e5, e6, e7;
      if (k == 88) {
        float2u q = *reinterpret_cast<const float2u*>(xr + 92);
        e4 = q[0]; e5 = q[1]; e6 = xr[94]; e7 = 0.f;
      } else {
        float4u p1 = *reinterpret_cast<const float4u*>(xr + k + 4);
        e4 = p1[0]; e5 = p1[1]; e6 = p1[2]; e7 = p1[3];
      }
      afr[mt][kk] = make_uint4(pku(p0[0], p0[1]), pku(p0[2], p0[3]),
                               pku(e4, e5), pku(e6, e7));
    }
  }

  floatx4 acc[2][8] = {};
#pragma unroll
  for (int kk = 0; kk < 3; ++kk)
#pragma unroll
    for (int nt = 0; nt < 8; ++nt) {
      const _Float16* wrow = Wp + (size_t)(nb0 + nt * 16 + l15) * 96 + lg * 8;
      uint4 bfr = *reinterpret_cast<const uint4*>(wrow + kk * 32);
      half8 bv = __builtin_bit_cast(half8, bfr);
      acc[0][nt] = __builtin_amdgcn_mfma_f32_16x16x32_f16(
          __builtin_bit_cast(half8, afr[0][kk]), bv, acc[0][nt], 0, 0, 0);
      acc[1][nt] = __builtin_amdgcn_mfma_f32_16x16x32_f16(
          __builtin_bit_cast(half8, afr[1][kk]), bv, acc[1][nt], 0, 0, 0);
    }

#pragma unroll
  for (int nt = 0; nt < 8; ++nt) {
    int n = nb0 + nt * 16 + l15;
    float bias = biasp[n];
#pragma unroll
    for (int mt = 0; mt < 2; ++mt) {
      int rbase = row0 + mt * 16 + lg * 4;
#pragma unroll
      for (int r = 0; r < 4; ++r)
        xw[(size_t)(rbase + r) * G + n] = (_Float16)(acc[mt][nt][r] + bias);
    }
  }
}

// ---------------------------------------------------------------------------
// K2: dual-batch MFMA LSTM. Grid 128 x 512 thr (8 waves, 2/SIMD).
// Block handles batches {2B, 2B+1}. Wave W owns units 16W..16W+16 of BOTH
// batches: B-matrix cols carry the batch (B[k][n] = h_{n&1}[k]) -> only
// 16 MFMA per wave-step for two batch-steps (halves the MFMA-pipe term);
// 2 waves/SIMD interleave to fill chain stalls. afr[4][4] = 64 VGPR; total
// ~124 fits the 128-cap at 512 thr (r9-measured footprint, no spill).
// Lane: bb = l15&1 (batch), rr = (l15>>1)&3 (acc reg), l15>=8 duplicates.
// unit u = 16W + 4lg + rr. Extraction = 3 cndmask/gate on rr.
// ---------------------------------------------------------------------------
template <int TC>
__global__ __attribute__((amdgpu_flat_work_group_size(512, 512)))
void k2_lstm(const _Float16* __restrict__ xw, const float* __restrict__ W_hh,
             float* __restrict__ hstate, float* __restrict__ cstate,
             const float* __restrict__ fc_w, const float* __restrict__ fc_b,
             float* __restrict__ out, int t0) {
  __shared__ __align__(16) _Float16 h2[2][2][Hh];  // [batch][buf][unit]
  __shared__ float h32[2][Hh];

  const int tid = threadIdx.x;
  const int W = tid >> 6, lane = tid & 63;
  const int l15 = lane & 15, lg = lane >> 4;
  const int bb = l15 & 1;               // batch bit
  const int rr = (l15 >> 1) & 3;        // acc reg selector
  const int u = 16 * W + 4 * lg + rr;   // unit this lane updates
  const int b = blockIdx.x * 2 + bb;
  const bool owner = (l15 < 8);         // one lane per (batch,unit) per lg

  // A-fragments: 4 tiles (gate q) x 4 kc; rows q*128 + 16W + l15 -> 64 VGPR
  uint4 afr[4][4];
#pragma unroll
  for (int q = 0; q < 4; ++q) {
    const float* wr = W_hh + (size_t)(q * 128 + 16 * W + l15) * Hh + 8 * lg;
#pragma unroll
    for (int kc = 0; kc < 4; ++kc) {
      float4u p0 = *reinterpret_cast<const float4u*>(wr + 32 * kc);
      float4u p1 = *reinterpret_cast<const float4u*>(wr + 32 * kc + 4);
      afr[q][kc] = make_uint4(pku(p0[0], p0[1]), pku(p0[2], p0[3]),
                              pku(p1[0], p1[1]), pku(p1[2], p1[3]));
    }
  }

  float creg = 0.f, hreg = 0.f;
  if (t0 == 0) {
    if (owner && lg == 0) {
      // zero both buffers' worth via 8 writer lanes x ... simple: each owner
      // lane (bb,rr) with all lg zeroes its 4 units
    }
    if (owner) h2[bb][0][u] = (_Float16)0.f;
  } else {
    creg = cstate[b * Hh + u];
    hreg = hstate[b * Hh + u];
    if (owner) h2[bb][0][u] = (_Float16)hreg;
  }
  __syncthreads();

  const _Float16* xwb = xw + (size_t)b * TC * G + u;

  // 4-deep prefetch ring, raw f16 (cvt at consume — r12 lesson)
  _Float16 ri[4], rf[4], rg[4], ro[4];
#pragma unroll
  for (int i = 0; i < 4; ++i) {
    if (i < TC) {
      const _Float16* xp = xwb + (size_t)i * G;
      ri[i] = xp[0 * 128]; rf[i] = xp[1 * 128];
      rg[i] = xp[2 * 128]; ro[i] = xp[3 * 128];
    } else {
      ri[i] = rf[i] = rg[i] = ro[i] = (_Float16)0.f;
    }
  }

#define K2_STEP(TL, SL)                                                        \
  {                                                                            \
    const int tl_ = (TL);                                                      \
    const int rb_ = tl_ & 1;                                                   \
    float ci = (float)ri[SL], cf = (float)rf[SL];                              \
    float cg = (float)rg[SL], co = (float)ro[SL];                              \
    if (tl_ + 4 < TC) {                                                        \
      const _Float16* xp_ = xwb + (size_t)(tl_ + 4) * G;                       \
      ri[SL] = xp_[0 * 128]; rf[SL] = xp_[1 * 128];                            \
      rg[SL] = xp_[2 * 128]; ro[SL] = xp_[3 * 128];                            \
    }                                                                          \
    uint4 bfr[4];                                                              \
    _Pragma("unroll") for (int kc = 0; kc < 4; ++kc) bfr[kc] =                 \
        *reinterpret_cast<const uint4*>(&h2[bb][rb_][32 * kc + 8 * lg]);       \
    floatx4 acc[4] = {};                                                       \
    _Pragma("unroll") for (int kc = 0; kc < 4; ++kc)                           \
        _Pragma("unroll") for (int q_ = 0; q_ < 4; ++q_)                       \
            acc[q_] = __builtin_amdgcn_mfma_f32_16x16x32_f16(                  \
                __builtin_bit_cast(half8, afr[q_][kc]),                        \
                __builtin_bit_cast(half8, bfr[kc]), acc[q_], 0, 0, 0);         \
    float gq[4];                                                               \
    _Pragma("unroll") for (int q_ = 0; q_ < 4; ++q_) {                         \
      float lo = (rr & 1) ? acc[q_][1] : acc[q_][0];                           \
      float hi = (rr & 1) ? acc[q_][3] : acc[q_][2];                           \
      gq[q_] = (rr & 2) ? hi : lo;                                             \
    }                                                                          \
    float i_ = fsigm(gq[0] + ci);                                              \
    float f_ = fsigm(gq[1] + cf);                                              \
    float g_ = ftanh2(gq[2] + cg);                                             \
    float o_ = fsigm(gq[3] + co);                                              \
    creg = fmaf(f_, creg, i_ * g_);                                            \
    hreg = o_ * ftanh2(creg);                                                  \
    if (owner) h2[bb][rb_ ^ 1][u] = (_Float16)hreg;                            \
    asm volatile("s_waitcnt lgkmcnt(0)" ::: "memory");                         \
    __builtin_amdgcn_s_barrier();                                              \
    __builtin_amdgcn_sched_barrier(0);                                         \
  }

  int tl = 0;
  for (; tl + 4 <= TC; tl += 4) {
    K2_STEP(tl + 0, 0)
    K2_STEP(tl + 1, 1)
    K2_STEP(tl + 2, 2)
    K2_STEP(tl + 3, 3)
  }
  if constexpr ((TC & 3) >= 1) K2_STEP(TC & ~3, 0)
  if constexpr ((TC & 3) >= 2) K2_STEP((TC & ~3) + 1, 1)
  if constexpr ((TC & 3) >= 3) K2_STEP((TC & ~3) + 2, 2)
#undef K2_STEP

  if (owner) {
    hstate[b * Hh + u] = hreg;
    cstate[b * Hh + u] = creg;
    h32[bb][u] = hreg;
  }
  __syncthreads();

  // Final FC (2 batches x 4 outputs per block)
  if (t0 + TC == Tt && tid < 8) {
    int s2 = tid >> 2, g = tid & 3;
    int bo = blockIdx.x * 2 + s2;
    float s = fc_b[g];
    for (int jj = 0; jj < Hh; ++jj)
      s = fmaf(h32[s2][jj], fc_w[g * Hh + jj], s);
    out[bo * 4 + g] = s;
  }
}

// ---------------------------------------------------------------------------
template <int TC>
static void run_chunks(const float* x, const float* gamma, const float* beta,
                       const float* rmean, const float* rvar,
                       const float* W_ih, const float* W_hh,
                       const float* b_ih, const float* b_hh,
                       const float* fc_w, const float* fc_b, float* out,
                       void* d_ws, hipStream_t stream) {
  char* ws = reinterpret_cast<char*>(d_ws);
  _Float16* xwp = reinterpret_cast<_Float16*>(ws);
  size_t off = (size_t)Bb * TC * G * 4;  // f32-sized reservation (safe)
  float* hst = reinterpret_cast<float*>(ws + off);  off += (size_t)Bb * Hh * 4;
  float* cst = reinterpret_cast<float*>(ws + off);  off += (size_t)Bb * Hh * 4;
  float* bia = reinterpret_cast<float*>(ws + off);  off += 512 * 4;
  off = (off + 15) & ~(size_t)15;
  _Float16* Wp = reinterpret_cast<_Float16*>(ws + off);

  k0_prep<<<dim3(1), dim3(512), 0, stream>>>(gamma, beta, rmean, rvar, W_ih,
                                             b_ih, b_hh, bia, Wp);
  for (int t0 = 0; t0 < Tt; t0 += TC) {
    k1_mfma<TC><<<dim3(Bb * TC / 64), dim3(512), 0, stream>>>(x, Wp, bia, xwp,
                                                              t0);
    k2_lstm<TC><<<dim3(Bb / 2), dim3(512), 0, stream>>>(xwp, W_hh, hst, cst,
                                                        fc_w, fc_b, out, t0);
  }
}

extern "C" void kernel_launch(void* const* d_in, const int* in_sizes, int n_in,
                              void* d_out, int out_size, void* d_ws,
                              size_t ws_size, hipStream_t stream) {
  const float* x     = (const float*)d_in[0];
  const float* gamma = (const float*)d_in[1];
  const float* beta  = (const float*)d_in[2];
  const float* rmean = (const float*)d_in[3];
  const float* rvar  = (const float*)d_in[4];
  const float* W_ih  = (const float*)d_in[5];
  const float* W_hh  = (const float*)d_in[6];
  const float* b_ih  = (const float*)d_in[7];
  const float* b_hh  = (const float*)d_in[8];
  const float* fc_w  = (const float*)d_in[9];
  const float* fc_b  = (const float*)d_in[10];
  float* out = (float*)d_out;

  auto need = [](int tc) {
    return (size_t)Bb * tc * G * 4 + 2 * (size_t)Bb * Hh * 4 + 512 * 4 + 16 +
           (size_t)512 * 96 * 2;
  };

  if (ws_size >= need(250)) {
    run_chunks<250>(x, gamma, beta, rmean, rvar, W_ih, W_hh, b_ih, b_hh, fc_w,
                    fc_b, out, d_ws, stream);
  } else if (ws_size >= need(125)) {
    run_chunks<125>(x, gamma, beta, rmean, rvar, W_ih, W_hh, b_ih, b_hh, fc_w,
                    fc_b, out, d_ws, stream);
  } else if (ws_size >= need(50)) {
    run_chunks<50>(x, gamma, beta, rmean, rvar, W_ih, W_hh, b_ih, b_hh, fc_w,
                   fc_b, out, d_ws, stream);
  } else {
    run_chunks<10>(x, gamma, beta, rmean, rvar, W_ih, W_hh, b_ih, b_hh, fc_w,
                   fc_b, out, d_ws, stream);
  }
}

// Round 15
// 809.114 us; speedup vs baseline: 1.3072x; 1.1131x over previous
//
#include <hip/hip_runtime.h>
#include <cstdint>

// Problem constants
constexpr int Cc = 95;    // input channels
constexpr int Hh = 128;   // hidden
constexpr int G  = 512;   // 4*H gates
constexpr int Bb = 256;   // batch
constexpr int Tt = 1000;  // timesteps
#define EPSBN 1e-5f

typedef _Float16 half8  __attribute__((ext_vector_type(8)));
typedef float floatx4 __attribute__((ext_vector_type(4)));
typedef float float4u __attribute__((ext_vector_type(4), aligned(4)));
typedef float float2u __attribute__((ext_vector_type(2), aligned(4)));

__device__ __forceinline__ unsigned pku(float a, float b) {
  return __builtin_bit_cast(unsigned, __builtin_amdgcn_cvt_pkrtz(a, b));
}
__device__ __forceinline__ float fsigm(float y) {
  y = fminf(30.f, fmaxf(-30.f, y));
  float e = __expf(-y);
  return __fdividef(1.f, 1.f + e);
}
__device__ __forceinline__ float ftanh2(float x) {  // tanh via exp(2x)
  float y = fminf(30.f, fmaxf(-30.f, 2.f * x));
  float e = __expf(y);
  return __fdividef(e - 1.f, e + 1.f);
}

// ---------------------------------------------------------------------------
// K0: fold BN into W_ih -> Wp f16 [512][96] (k=95 padded 0),
// bias'[g] = b_ih+b_hh + sum_c sft_c * W_ih[g][c].
// ---------------------------------------------------------------------------
__global__ __launch_bounds__(512)
void k0_prep(const float* __restrict__ gamma, const float* __restrict__ beta,
             const float* __restrict__ rmean, const float* __restrict__ rvar,
             const float* __restrict__ W_ih, const float* __restrict__ b_ih,
             const float* __restrict__ b_hh, float* __restrict__ biasp,
             _Float16* __restrict__ Wp) {
  __shared__ float scl[Cc], sft[Cc];
  const int t = threadIdx.x;
  if (t < Cc) {
    float s = gamma[t] * rsqrtf(rvar[t] + EPSBN);
    scl[t] = s;
    sft[t] = beta[t] - rmean[t] * s;
  }
  __syncthreads();
  float acc = b_ih[t] + b_hh[t];
  const float* wr = W_ih + (size_t)t * Cc;
  for (int c = 0; c < Cc; ++c) {
    float w = wr[c];
    acc = fmaf(sft[c], w, acc);
    Wp[t * 96 + c] = (_Float16)(w * scl[c]);
  }
  Wp[t * 96 + 95] = (_Float16)0.f;
  biasp[t] = acc;
}

// ---------------------------------------------------------------------------
// K12 fused kernel, 256 threads (4 waves), grid = n_k2 + n_k1 blocks.
//  - blocks [0, n_k2): K2 role — LSTM recurrence chunk t0r (r8-proven step,
//    f16 xw, raw-f16 4-deep ring with cvt-at-consume). 1 batch/CU.
//  - blocks [n_k2, ...): K1 role — GEMM of chunk t0g into xw_w (f16).
//    32 rows x 512 cols per block; these waves backfill the k2 blocks'
//    idle issue slots (independent co-resident waves overlap, m114),
//    hiding the GEMM entirely under the recurrence interval.
// Cross-dispatch xw dependency handled by kernel-boundary release/acquire.
// ---------------------------------------------------------------------------
template <int TC>
__global__ __launch_bounds__(256, 1)
void k12(const float* __restrict__ x, const _Float16* __restrict__ Wp,
         const float* __restrict__ biasp, const float* __restrict__ W_hh,
         const _Float16* __restrict__ xw_r, _Float16* __restrict__ xw_w,
         float* __restrict__ hstate, float* __restrict__ cstate,
         const float* __restrict__ fc_w, const float* __restrict__ fc_b,
         float* __restrict__ out, int n_k2, int t0r, int t0g) {
  const int tid = threadIdx.x;

  if ((int)blockIdx.x >= n_k2) {
    // ---------------- K1 role: GEMM 32 rows x 512 gate-cols ----------------
    const int blk = blockIdx.x - n_k2;
    const int wave = tid >> 6, lane = tid & 63;
    const int nb0 = wave * 128;
    const int row0 = blk * 32;
    const int l15 = lane & 15, lg = lane >> 4;

    uint4 afr[2][3];
#pragma unroll
    for (int mt = 0; mt < 2; ++mt) {
      int m = row0 + mt * 16 + l15;
      int b = m / TC, tl = m - b * TC;
      const float* xr = x + ((size_t)b * Tt + t0g + tl) * Cc;
#pragma unroll
      for (int kk = 0; kk < 3; ++kk) {
        int k = kk * 32 + lg * 8;
        float4u p0 = *reinterpret_cast<const float4u*>(xr + k);
        float e4, e5, e6, e7;
        if (k == 88) {
          float2u q = *reinterpret_cast<const float2u*>(xr + 92);
          e4 = q[0]; e5 = q[1]; e6 = xr[94]; e7 = 0.f;
        } else {
          float4u p1 = *reinterpret_cast<const float4u*>(xr + k + 4);
          e4 = p1[0]; e5 = p1[1]; e6 = p1[2]; e7 = p1[3];
        }
        afr[mt][kk] = make_uint4(pku(p0[0], p0[1]), pku(p0[2], p0[3]),
                                 pku(e4, e5), pku(e6, e7));
      }
    }

    floatx4 acc[2][8] = {};
#pragma unroll
    for (int kk = 0; kk < 3; ++kk)
#pragma unroll
      for (int nt = 0; nt < 8; ++nt) {
        const _Float16* wrow = Wp + (size_t)(nb0 + nt * 16 + l15) * 96 + lg * 8;
        uint4 bfr = *reinterpret_cast<const uint4*>(wrow + kk * 32);
        half8 bv = __builtin_bit_cast(half8, bfr);
        acc[0][nt] = __builtin_amdgcn_mfma_f32_16x16x32_f16(
            __builtin_bit_cast(half8, afr[0][kk]), bv, acc[0][nt], 0, 0, 0);
        acc[1][nt] = __builtin_amdgcn_mfma_f32_16x16x32_f16(
            __builtin_bit_cast(half8, afr[1][kk]), bv, acc[1][nt], 0, 0, 0);
      }

#pragma unroll
    for (int nt = 0; nt < 8; ++nt) {
      int n = nb0 + nt * 16 + l15;
      float bias = biasp[n];
#pragma unroll
      for (int mt = 0; mt < 2; ++mt) {
        int rbase = row0 + mt * 16 + lg * 4;
#pragma unroll
        for (int r = 0; r < 4; ++r)
          xw_w[(size_t)(rbase + r) * G + n] = (_Float16)(acc[mt][nt][r] + bias);
      }
    }
    return;
  }

  // ------------------- K2 role: LSTM recurrence (r8 step) -------------------
  __shared__ __align__(16) _Float16 h2[2][Hh];
  __shared__ float h32[Hh];

  const int b = blockIdx.x;
  const int w = tid >> 6, lane = tid & 63;
  const int l15 = lane & 15, lg = lane >> 4;
  const int hh = l15 & 1, rr = (l15 >> 1) & 3;   // l15>=8 duplicates
  const int u = 32 * w + 16 * hh + 4 * lg + rr;  // unit this lane updates
  const bool owner = (l15 < 8);

  // A-fragments: W_hh rows (f16) 8 tiles x 4 k-chunks -> 128 VGPRs
  uint4 afr[8][4];
#pragma unroll
  for (int q = 0; q < 4; ++q)
#pragma unroll
    for (int h2i = 0; h2i < 2; ++h2i) {
      const float* wr =
          W_hh + (size_t)(q * 128 + 32 * w + 16 * h2i + l15) * Hh + 8 * lg;
#pragma unroll
      for (int kc = 0; kc < 4; ++kc) {
        float4u p0 = *reinterpret_cast<const float4u*>(wr + 32 * kc);
        float4u p1 = *reinterpret_cast<const float4u*>(wr + 32 * kc + 4);
        afr[2 * q + h2i][kc] = make_uint4(pku(p0[0], p0[1]), pku(p0[2], p0[3]),
                                          pku(p1[0], p1[1]), pku(p1[2], p1[3]));
      }
    }

  float creg = 0.f, hreg = 0.f;
  if (t0r == 0) {
    if (owner) h2[0][u] = (_Float16)0.f;
  } else {
    creg = cstate[b * Hh + u];
    hreg = hstate[b * Hh + u];
    if (owner) h2[0][u] = (_Float16)hreg;
  }
  __syncthreads();

  const _Float16* xwb = xw_r + (size_t)b * TC * G + u;

  // 4-deep prefetch ring, raw f16 (cvt at consume — r12 lesson)
  _Float16 ri[4], rf[4], rg[4], ro[4];
#pragma unroll
  for (int i = 0; i < 4; ++i) {
    if (i < TC) {
      const _Float16* xp = xwb + (size_t)i * G;
      ri[i] = xp[0 * 128]; rf[i] = xp[1 * 128];
      rg[i] = xp[2 * 128]; ro[i] = xp[3 * 128];
    } else {
      ri[i] = rf[i] = rg[i] = ro[i] = (_Float16)0.f;
    }
  }

#define K2_STEP(TL, SL)                                                        \
  {                                                                            \
    const int tl_ = (TL);                                                      \
    const int rb_ = tl_ & 1;                                                   \
    float ci = (float)ri[SL], cf = (float)rf[SL];                              \
    float cg = (float)rg[SL], co = (float)ro[SL];                              \
    if (tl_ + 4 < TC) {                                                        \
      const _Float16* xp_ = xwb + (size_t)(tl_ + 4) * G;                       \
      ri[SL] = xp_[0 * 128]; rf[SL] = xp_[1 * 128];                            \
      rg[SL] = xp_[2 * 128]; ro[SL] = xp_[3 * 128];                            \
    }                                                                          \
    uint4 bfr[4];                                                              \
    _Pragma("unroll") for (int kc = 0; kc < 4; ++kc)                           \
        bfr[kc] = *reinterpret_cast<const uint4*>(&h2[rb_][32 * kc + 8 * lg]); \
    floatx4 acc[8] = {};                                                       \
    _Pragma("unroll") for (int kc = 0; kc < 4; ++kc)                           \
        _Pragma("unroll") for (int t_ = 0; t_ < 8; ++t_)                       \
            acc[t_] = __builtin_amdgcn_mfma_f32_16x16x32_f16(                  \
                __builtin_bit_cast(half8, afr[t_][kc]),                        \
                __builtin_bit_cast(half8, bfr[kc]), acc[t_], 0, 0, 0);         \
    float gq[4];                                                               \
    _Pragma("unroll") for (int q_ = 0; q_ < 4; ++q_) {                         \
      float e0 = hh ? acc[2 * q_ + 1][0] : acc[2 * q_][0];                     \
      float e1 = hh ? acc[2 * q_ + 1][1] : acc[2 * q_][1];                     \
      float e2 = hh ? acc[2 * q_ + 1][2] : acc[2 * q_][2];                     \
      float e3 = hh ? acc[2 * q_ + 1][3] : acc[2 * q_][3];                     \
      float lo = (rr & 1) ? e1 : e0;                                           \
      float hi = (rr & 1) ? e3 : e2;                                           \
      gq[q_] = (rr & 2) ? hi : lo;                                             \
    }                                                                          \
    float i_ = fsigm(gq[0] + ci);                                              \
    float f_ = fsigm(gq[1] + cf);                                              \
    float g_ = ftanh2(gq[2] + cg);                                             \
    float o_ = fsigm(gq[3] + co);                                              \
    creg = fmaf(f_, creg, i_ * g_);                                            \
    hreg = o_ * ftanh2(creg);                                                  \
    if (owner) h2[rb_ ^ 1][u] = (_Float16)hreg;                                \
    asm volatile("s_waitcnt lgkmcnt(0)" ::: "memory");                         \
    __builtin_amdgcn_s_barrier();                                              \
    __builtin_amdgcn_sched_barrier(0);                                         \
  }

  int tl = 0;
  for (; tl + 4 <= TC; tl += 4) {
    K2_STEP(tl + 0, 0)
    K2_STEP(tl + 1, 1)
    K2_STEP(tl + 2, 2)
    K2_STEP(tl + 3, 3)
  }
  if constexpr ((TC & 3) >= 1) K2_STEP(TC & ~3, 0)
  if constexpr ((TC & 3) >= 2) K2_STEP((TC & ~3) + 1, 1)
  if constexpr ((TC & 3) >= 3) K2_STEP((TC & ~3) + 2, 2)
#undef K2_STEP

  if (owner) {
    hstate[b * Hh + u] = hreg;
    cstate[b * Hh + u] = creg;
    h32[u] = hreg;
  }
  __syncthreads();

  if (t0r + TC == Tt && tid < 4) {
    float s = fc_b[tid];
    for (int jj = 0; jj < Hh; ++jj) s = fmaf(h32[jj], fc_w[tid * Hh + jj], s);
    out[b * 4 + tid] = s;
  }
}

// ---------------------------------------------------------------------------
template <int TC>
static void run_all(const float* x, const float* gamma, const float* beta,
                    const float* rmean, const float* rvar, const float* W_ih,
                    const float* W_hh, const float* b_ih, const float* b_hh,
                    const float* fc_w, const float* fc_b, float* out,
                    void* d_ws, hipStream_t stream) {
  char* ws = reinterpret_cast<char*>(d_ws);
  const size_t SX = (size_t)Bb * TC * G * 2;  // f16 xw buffer bytes
  _Float16* xwA = reinterpret_cast<_Float16*>(ws);
  _Float16* xwB = reinterpret_cast<_Float16*>(ws + SX);
  size_t off = 2 * SX;
  float* hst = reinterpret_cast<float*>(ws + off);  off += (size_t)Bb * Hh * 4;
  float* cst = reinterpret_cast<float*>(ws + off);  off += (size_t)Bb * Hh * 4;
  float* bia = reinterpret_cast<float*>(ws + off);  off += 512 * 4;
  off = (off + 15) & ~(size_t)15;
  _Float16* Wp = reinterpret_cast<_Float16*>(ws + off);

  constexpr int NCH = Tt / TC;
  constexpr int NK1 = Bb * TC / 32;  // GEMM blocks per chunk

  k0_prep<<<dim3(1), dim3(512), 0, stream>>>(gamma, beta, rmean, rvar, W_ih,
                                             b_ih, b_hh, bia, Wp);
  // Prologue: GEMM chunk 0 only
  k12<TC><<<dim3(NK1), dim3(256), 0, stream>>>(
      x, Wp, bia, W_hh, nullptr, xwA, hst, cst, fc_w, fc_b, out, 0, 0, 0);

  _Float16* bufs[2] = {xwA, xwB};
  for (int c = 0; c < NCH; ++c) {
    const bool last = (c == NCH - 1);
    int grid = 256 + (last ? 0 : NK1);
    k12<TC><<<dim3(grid), dim3(256), 0, stream>>>(
        x, Wp, bia, W_hh, bufs[c & 1], bufs[(c + 1) & 1], hst, cst, fc_w, fc_b,
        out, 256, c * TC, (c + 1) * TC);
  }
}

extern "C" void kernel_launch(void* const* d_in, const int* in_sizes, int n_in,
                              void* d_out, int out_size, void* d_ws,
                              size_t ws_size, hipStream_t stream) {
  const float* x     = (const float*)d_in[0];
  const float* gamma = (const float*)d_in[1];
  const float* beta  = (const float*)d_in[2];
  const float* rmean = (const float*)d_in[3];
  const float* rvar  = (const float*)d_in[4];
  const float* W_ih  = (const float*)d_in[5];
  const float* W_hh  = (const float*)d_in[6];
  const float* b_ih  = (const float*)d_in[7];
  const float* b_hh  = (const float*)d_in[8];
  const float* fc_w  = (const float*)d_in[9];
  const float* fc_b  = (const float*)d_in[10];
  float* out = (float*)d_out;

  auto need = [](int tc) {
    return 2 * (size_t)Bb * tc * G * 2 + 2 * (size_t)Bb * Hh * 4 + 512 * 4 +
           16 + (size_t)512 * 96 * 2;
  };

  if (ws_size >= need(250)) {
    run_all<250>(x, gamma, beta, rmean, rvar, W_ih, W_hh, b_ih, b_hh, fc_w,
                 fc_b, out, d_ws, stream);
  } else if (ws_size >= need(125)) {
    run_all<125>(x, gamma, beta, rmean, rvar, W_ih, W_hh, b_ih, b_hh, fc_w,
                 fc_b, out, d_ws, stream);
  } else if (ws_size >= need(50)) {
    run_all<50>(x, gamma, beta, rmean, rvar, W_ih, W_hh, b_ih, b_hh, fc_w,
                fc_b, out, d_ws, stream);
  } else {
    run_all<10>(x, gamma, beta, rmean, rvar, W_ih, W_hh, b_ih, b_hh, fc_w,
                fc_b, out, d_ws, stream);
  }
}

// Round 16
// 802.310 us; speedup vs baseline: 1.3183x; 1.0085x over previous
//
#include <hip/hip_runtime.h>
#include <cstdint>

// Problem constants
constexpr int Cc = 95;    // input channels
constexpr int Hh = 128;   // hidden
constexpr int G  = 512;   // 4*H gates
constexpr int Bb = 256;   // batch
constexpr int Tt = 1000;  // timesteps
#define EPSBN 1e-5f

typedef _Float16 half8  __attribute__((ext_vector_type(8)));
typedef float floatx4 __attribute__((ext_vector_type(4)));
typedef float float4u __attribute__((ext_vector_type(4), aligned(4)));
typedef float float2u __attribute__((ext_vector_type(2), aligned(4)));

__device__ __forceinline__ unsigned pku(float a, float b) {
  return __builtin_bit_cast(unsigned, __builtin_amdgcn_cvt_pkrtz(a, b));
}
__device__ __forceinline__ float fsigm(float y) {
  y = fminf(30.f, fmaxf(-30.f, y));
  float e = __expf(-y);
  return __fdividef(1.f, 1.f + e);
}
__device__ __forceinline__ float ftanh2(float x) {  // tanh via exp(2x)
  float y = fminf(30.f, fmaxf(-30.f, 2.f * x));
  float e = __expf(y);
  return __fdividef(e - 1.f, e + 1.f);
}

// ---------------------------------------------------------------------------
// K0: fold BN into W_ih -> Wp f16 [512][96] (k=95 padded 0),
// bias'[g] = b_ih+b_hh + sum_c sft_c * W_ih[g][c].
// ---------------------------------------------------------------------------
__global__ __launch_bounds__(512)
void k0_prep(const float* __restrict__ gamma, const float* __restrict__ beta,
             const float* __restrict__ rmean, const float* __restrict__ rvar,
             const float* __restrict__ W_ih, const float* __restrict__ b_ih,
             const float* __restrict__ b_hh, float* __restrict__ biasp,
             _Float16* __restrict__ Wp) {
  __shared__ float scl[Cc], sft[Cc];
  const int t = threadIdx.x;
  if (t < Cc) {
    float s = gamma[t] * rsqrtf(rvar[t] + EPSBN);
    scl[t] = s;
    sft[t] = beta[t] - rmean[t] * s;
  }
  __syncthreads();
  float acc = b_ih[t] + b_hh[t];
  const float* wr = W_ih + (size_t)t * Cc;
  for (int c = 0; c < Cc; ++c) {
    float w = wr[c];
    acc = fmaf(sft[c], w, acc);
    Wp[t * 96 + c] = (_Float16)(w * scl[c]);
  }
  Wp[t * 96 + 95] = (_Float16)0.f;
  biasp[t] = acc;
}

// ---------------------------------------------------------------------------
// K12 fused kernel, 256 threads (4 waves), grid = n_k2 + n_k1 blocks.
//  - blocks [0, n_k2): K2 role — LSTM recurrence chunk t0r (r8-proven step,
//    f16 xw, raw-f16 4-deep ring with cvt-at-consume). 1 batch/CU.
//    Runs at s_setprio(1): the recurrence chain is latency-critical; CU
//    arbitration must prefer it whenever it has a ready instruction (T5 —
//    heterogeneous wave roles on one SIMD).
//  - blocks [n_k2, ...): K1 role — GEMM of chunk t0g into xw_w (f16), at
//    default prio 0: fills only the k2 waves' true stall slots.
// Cross-dispatch xw dependency handled by kernel-boundary release/acquire.
// ---------------------------------------------------------------------------
template <int TC>
__global__ __launch_bounds__(256, 1)
void k12(const float* __restrict__ x, const _Float16* __restrict__ Wp,
         const float* __restrict__ biasp, const float* __restrict__ W_hh,
         const _Float16* __restrict__ xw_r, _Float16* __restrict__ xw_w,
         float* __restrict__ hstate, float* __restrict__ cstate,
         const float* __restrict__ fc_w, const float* __restrict__ fc_b,
         float* __restrict__ out, int n_k2, int t0r, int t0g) {
  const int tid = threadIdx.x;

  if ((int)blockIdx.x >= n_k2) {
    // ---------------- K1 role: GEMM 32 rows x 512 gate-cols ----------------
    const int blk = blockIdx.x - n_k2;
    const int wave = tid >> 6, lane = tid & 63;
    const int nb0 = wave * 128;
    const int row0 = blk * 32;
    const int l15 = lane & 15, lg = lane >> 4;

    uint4 afr[2][3];
#pragma unroll
    for (int mt = 0; mt < 2; ++mt) {
      int m = row0 + mt * 16 + l15;
      int b = m / TC, tl = m - b * TC;
      const float* xr = x + ((size_t)b * Tt + t0g + tl) * Cc;
#pragma unroll
      for (int kk = 0; kk < 3; ++kk) {
        int k = kk * 32 + lg * 8;
        float4u p0 = *reinterpret_cast<const float4u*>(xr + k);
        float e4, e5, e6, e7;
        if (k == 88) {
          float2u q = *reinterpret_cast<const float2u*>(xr + 92);
          e4 = q[0]; e5 = q[1]; e6 = xr[94]; e7 = 0.f;
        } else {
          float4u p1 = *reinterpret_cast<const float4u*>(xr + k + 4);
          e4 = p1[0]; e5 = p1[1]; e6 = p1[2]; e7 = p1[3];
        }
        afr[mt][kk] = make_uint4(pku(p0[0], p0[1]), pku(p0[2], p0[3]),
                                 pku(e4, e5), pku(e6, e7));
      }
    }

    floatx4 acc[2][8] = {};
#pragma unroll
    for (int kk = 0; kk < 3; ++kk)
#pragma unroll
      for (int nt = 0; nt < 8; ++nt) {
        const _Float16* wrow = Wp + (size_t)(nb0 + nt * 16 + l15) * 96 + lg * 8;
        uint4 bfr = *reinterpret_cast<const uint4*>(wrow + kk * 32);
        half8 bv = __builtin_bit_cast(half8, bfr);
        acc[0][nt] = __builtin_amdgcn_mfma_f32_16x16x32_f16(
            __builtin_bit_cast(half8, afr[0][kk]), bv, acc[0][nt], 0, 0, 0);
        acc[1][nt] = __builtin_amdgcn_mfma_f32_16x16x32_f16(
            __builtin_bit_cast(half8, afr[1][kk]), bv, acc[1][nt], 0, 0, 0);
      }

#pragma unroll
    for (int nt = 0; nt < 8; ++nt) {
      int n = nb0 + nt * 16 + l15;
      float bias = biasp[n];
#pragma unroll
      for (int mt = 0; mt < 2; ++mt) {
        int rbase = row0 + mt * 16 + lg * 4;
#pragma unroll
        for (int r = 0; r < 4; ++r)
          xw_w[(size_t)(rbase + r) * G + n] = (_Float16)(acc[mt][nt][r] + bias);
      }
    }
    return;
  }

  // ------------------- K2 role: LSTM recurrence (r8 step) -------------------
  __builtin_amdgcn_s_setprio(1);  // T5: favor the latency-critical chain

  __shared__ __align__(16) _Float16 h2[2][Hh];
  __shared__ float h32[Hh];

  const int b = blockIdx.x;
  const int w = tid >> 6, lane = tid & 63;
  const int l15 = lane & 15, lg = lane >> 4;
  const int hh = l15 & 1, rr = (l15 >> 1) & 3;   // l15>=8 duplicates
  const int u = 32 * w + 16 * hh + 4 * lg + rr;  // unit this lane updates
  const bool owner = (l15 < 8);

  // A-fragments: W_hh rows (f16) 8 tiles x 4 k-chunks -> 128 VGPRs
  uint4 afr[8][4];
#pragma unroll
  for (int q = 0; q < 4; ++q)
#pragma unroll
    for (int h2i = 0; h2i < 2; ++h2i) {
      const float* wr =
          W_hh + (size_t)(q * 128 + 32 * w + 16 * h2i + l15) * Hh + 8 * lg;
#pragma unroll
      for (int kc = 0; kc < 4; ++kc) {
        float4u p0 = *reinterpret_cast<const float4u*>(wr + 32 * kc);
        float4u p1 = *reinterpret_cast<const float4u*>(wr + 32 * kc + 4);
        afr[2 * q + h2i][kc] = make_uint4(pku(p0[0], p0[1]), pku(p0[2], p0[3]),
                                          pku(p1[0], p1[1]), pku(p1[2], p1[3]));
      }
    }

  float creg = 0.f, hreg = 0.f;
  if (t0r == 0) {
    if (owner) h2[0][u] = (_Float16)0.f;
  } else {
    creg = cstate[b * Hh + u];
    hreg = hstate[b * Hh + u];
    if (owner) h2[0][u] = (_Float16)hreg;
  }
  __syncthreads();

  const _Float16* xwb = xw_r + (size_t)b * TC * G + u;

  // 4-deep prefetch ring, raw f16 (cvt at consume — r12 lesson)
  _Float16 ri[4], rf[4], rg[4], ro[4];
#pragma unroll
  for (int i = 0; i < 4; ++i) {
    if (i < TC) {
      const _Float16* xp = xwb + (size_t)i * G;
      ri[i] = xp[0 * 128]; rf[i] = xp[1 * 128];
      rg[i] = xp[2 * 128]; ro[i] = xp[3 * 128];
    } else {
      ri[i] = rf[i] = rg[i] = ro[i] = (_Float16)0.f;
    }
  }

#define K2_STEP(TL, SL)                                                        \
  {                                                                            \
    const int tl_ = (TL);                                                      \
    const int rb_ = tl_ & 1;                                                   \
    float ci = (float)ri[SL], cf = (float)rf[SL];                              \
    float cg = (float)rg[SL], co = (float)ro[SL];                              \
    if (tl_ + 4 < TC) {                                                        \
      const _Float16* xp_ = xwb + (size_t)(tl_ + 4) * G;                       \
      ri[SL] = xp_[0 * 128]; rf[SL] = xp_[1 * 128];                            \
      rg[SL] = xp_[2 * 128]; ro[SL] = xp_[3 * 128];                            \
    }                                                                          \
    uint4 bfr[4];                                                              \
    _Pragma("unroll") for (int kc = 0; kc < 4; ++kc)                           \
        bfr[kc] = *reinterpret_cast<const uint4*>(&h2[rb_][32 * kc + 8 * lg]); \
    floatx4 acc[8] = {};                                                       \
    _Pragma("unroll") for (int kc = 0; kc < 4; ++kc)                           \
        _Pragma("unroll") for (int t_ = 0; t_ < 8; ++t_)                       \
            acc[t_] = __builtin_amdgcn_mfma_f32_16x16x32_f16(                  \
                __builtin_bit_cast(half8, afr[t_][kc]),                        \
                __builtin_bit_cast(half8, bfr[kc]), acc[t_], 0, 0, 0);         \
    float gq[4];                                                               \
    _Pragma("unroll") for (int q_ = 0; q_ < 4; ++q_) {                         \
      float e0 = hh ? acc[2 * q_ + 1][0] : acc[2 * q_][0];                     \
      float e1 = hh ? acc[2 * q_ + 1][1] : acc[2 * q_][1];                     \
      float e2 = hh ? acc[2 * q_ + 1][2] : acc[2 * q_][2];                     \
      float e3 = hh ? acc[2 * q_ + 1][3] : acc[2 * q_][3];                     \
      float lo = (rr & 1) ? e1 : e0;                                           \
      float hi = (rr & 1) ? e3 : e2;                                           \
      gq[q_] = (rr & 2) ? hi : lo;                                             \
    }                                                                          \
    float i_ = fsigm(gq[0] + ci);                                              \
    float f_ = fsigm(gq[1] + cf);                                              \
    float g_ = ftanh2(gq[2] + cg);                                             \
    float o_ = fsigm(gq[3] + co);                                              \
    creg = fmaf(f_, creg, i_ * g_);                                            \
    hreg = o_ * ftanh2(creg);                                                  \
    if (owner) h2[rb_ ^ 1][u] = (_Float16)hreg;                                \
    asm volatile("s_waitcnt lgkmcnt(0)" ::: "memory");                         \
    __builtin_amdgcn_s_barrier();                                              \
    __builtin_amdgcn_sched_barrier(0);                                         \
  }

  int tl = 0;
  for (; tl + 4 <= TC; tl += 4) {
    K2_STEP(tl + 0, 0)
    K2_STEP(tl + 1, 1)
    K2_STEP(tl + 2, 2)
    K2_STEP(tl + 3, 3)
  }
  if constexpr ((TC & 3) >= 1) K2_STEP(TC & ~3, 0)
  if constexpr ((TC & 3) >= 2) K2_STEP((TC & ~3) + 1, 1)
  if constexpr ((TC & 3) >= 3) K2_STEP((TC & ~3) + 2, 2)
#undef K2_STEP

  __builtin_amdgcn_s_setprio(0);

  if (owner) {
    hstate[b * Hh + u] = hreg;
    cstate[b * Hh + u] = creg;
    h32[u] = hreg;
  }
  __syncthreads();

  if (t0r + TC == Tt && tid < 4) {
    float s = fc_b[tid];
    for (int jj = 0; jj < Hh; ++jj) s = fmaf(h32[jj], fc_w[tid * Hh + jj], s);
    out[b * 4 + tid] = s;
  }
}

// ---------------------------------------------------------------------------
template <int TC>
static void run_all(const float* x, const float* gamma, const float* beta,
                    const float* rmean, const float* rvar, const float* W_ih,
                    const float* W_hh, const float* b_ih, const float* b_hh,
                    const float* fc_w, const float* fc_b, float* out,
                    void* d_ws, hipStream_t stream) {
  char* ws = reinterpret_cast<char*>(d_ws);
  const size_t SX = (size_t)Bb * TC * G * 2;  // f16 xw buffer bytes
  _Float16* xwA = reinterpret_cast<_Float16*>(ws);
  _Float16* xwB = reinterpret_cast<_Float16*>(ws + SX);
  size_t off = 2 * SX;
  float* hst = reinterpret_cast<float*>(ws + off);  off += (size_t)Bb * Hh * 4;
  float* cst = reinterpret_cast<float*>(ws + off);  off += (size_t)Bb * Hh * 4;
  float* bia = reinterpret_cast<float*>(ws + off);  off += 512 * 4;
  off = (off + 15) & ~(size_t)15;
  _Float16* Wp = reinterpret_cast<_Float16*>(ws + off);

  constexpr int NCH = Tt / TC;
  constexpr int NK1 = Bb * TC / 32;  // GEMM blocks per chunk

  k0_prep<<<dim3(1), dim3(512), 0, stream>>>(gamma, beta, rmean, rvar, W_ih,
                                             b_ih, b_hh, bia, Wp);
  // Prologue: GEMM chunk 0 only
  k12<TC><<<dim3(NK1), dim3(256), 0, stream>>>(
      x, Wp, bia, W_hh, nullptr, xwA, hst, cst, fc_w, fc_b, out, 0, 0, 0);

  _Float16* bufs[2] = {xwA, xwB};
  for (int c = 0; c < NCH; ++c) {
    const bool last = (c == NCH - 1);
    int grid = 256 + (last ? 0 : NK1);
    k12<TC><<<dim3(grid), dim3(256), 0, stream>>>(
        x, Wp, bia, W_hh, bufs[c & 1], bufs[(c + 1) & 1], hst, cst, fc_w, fc_b,
        out, 256, c * TC, (c + 1) * TC);
  }
}

extern "C" void kernel_launch(void* const* d_in, const int* in_sizes, int n_in,
                              void* d_out, int out_size, void* d_ws,
                              size_t ws_size, hipStream_t stream) {
  const float* x     = (const float*)d_in[0];
  const float* gamma = (const float*)d_in[1];
  const float* beta  = (const float*)d_in[2];
  const float* rmean = (const float*)d_in[3];
  const float* rvar  = (const float*)d_in[4];
  const float* W_ih  = (const float*)d_in[5];
  const float* W_hh  = (const float*)d_in[6];
  const float* b_ih  = (const float*)d_in[7];
  const float* b_hh  = (const float*)d_in[8];
  const float* fc_w  = (const float*)d_in[9];
  const float* fc_b  = (const float*)d_in[10];
  float* out = (float*)d_out;

  auto need = [](int tc) {
    return 2 * (size_t)Bb * tc * G * 2 + 2 * (size_t)Bb * Hh * 4 + 512 * 4 +
           16 + (size_t)512 * 96 * 2;
  };

  if (ws_size >= need(250)) {
    run_all<250>(x, gamma, beta, rmean, rvar, W_ih, W_hh, b_ih, b_hh, fc_w,
                 fc_b, out, d_ws, stream);
  } else if (ws_size >= need(125)) {
    run_all<125>(x, gamma, beta, rmean, rvar, W_ih, W_hh, b_ih, b_hh, fc_w,
                 fc_b, out, d_ws, stream);
  } else if (ws_size >= need(50)) {
    run_all<50>(x, gamma, beta, rmean, rvar, W_ih, W_hh, b_ih, b_hh, fc_w,
                fc_b, out, d_ws, stream);
  } else {
    run_all<10>(x, gamma, beta, rmean, rvar, W_ih, W_hh, b_ih, b_hh, fc_w,
                fc_b, out, d_ws, stream);
  }
}